// Round 4
// baseline (88.146 us; speedup 1.0000x reference)
//
#include <hip/hip_runtime.h>

// IDW, POWER=2.0 -> w = 1/d2 (sqrt cancels). out = sum(w*v)/sum(w).
// B=2, P=131072, S=512.
// R9: post-mortem of R6/R7/R8: kernel ~=40us across {LDS+rotation,GPT2},
//     {SMEM,GPT2}, {SMEM,GPT1(4w/SIMD)} -> neither datapath nor TLP is the
//     lever. ~6 cyc/wave-inst at >=2 waves/SIMD = stall-bound on loads, and
//     NO previous variant ever built a deep load pipeline:
//       - manual rotation = forced 1-chunk lookahead + per-iter lgkm waits
//       - SMEM unroll-8 needs ~96 SGPRs/group in flight > ~102 budget ->
//         compiler can't pipeline across groups (load->waitcnt->compute).
//     Fix #1: LDS + DIRECT-indexed ds_read_b128, unroll 8, no rotation.
//     VGPR-based pipeline (24 reads x 12 VGPR ~ 116 in flight, fine at
//     2 waves/SIMD); compiler emits fine-grained lgkmcnt interleave (m97).
//     Fix #2: drop the rcp-combine trick. Trans pipe co-issues with VALU,
//     so minimizing rcp count by ADDING VALU ops was backwards. Direct
//     per-station rcp: 6 VALU + 1 trans/station (24+4 per quad) vs 31+1.
//     -22% VALU issue; 4 trans/quad (32cyc) hides under 48cyc VALU.
//     Dual accumulators (even/odd stations) break the wsum+=r serial chain.
// GPT=2 kept (best so far: amortizes each chunk over 2 points).
// EPS2 folded into d2 fma chain (exact at d2==0: w -> 1/EPS^2 like ref).

#define BLOCK 256
#define S_MAX 512
#define GPT 2

__global__ __launch_bounds__(BLOCK) void idw_kernel(
    const float* __restrict__ station_coords,  // (B, S, 2)
    const float* __restrict__ station_values,  // (B, S)
    const float* __restrict__ grid_points,     // (B, P, 2)
    float* __restrict__ out,                   // (B, P)
    int P, int S) {

    __shared__ float st[S_MAX * 3];  // packed {x,y,v}, 12B/station

    const int b = blockIdx.y;
    const float2* __restrict__ sc2 = (const float2*)(station_coords) + (size_t)b * S;
    const float*  __restrict__ svb = station_values + (size_t)b * S;

    for (int i = threadIdx.x; i < S; i += BLOCK) {
        const float2 c = sc2[i];
        st[3 * i + 0] = c.x;
        st[3 * i + 1] = c.y;
        st[3 * i + 2] = svb[i];
    }
    __syncthreads();

    const int tid = blockIdx.x * BLOCK + threadIdx.x;
    const float4 g01 = ((const float4*)grid_points)[(size_t)b * (P / 2) + tid];
    const float gx0 = g01.x, gy0 = g01.y, gx1 = g01.z, gy1 = g01.w;

    constexpr float EPS  = 1.1920928955078125e-07f;
    constexpr float EPS2 = EPS * EPS;

    // Dual accumulators per point: break the wsum += r dependence chain.
    float ws0a = 0.0f, vs0a = 0.0f, ws0b = 0.0f, vs0b = 0.0f;
    float ws1a = 0.0f, vs1a = 0.0f, ws1b = 0.0f, vs1b = 0.0f;

    const float4* __restrict__ st4 = (const float4*)st;

    // One station vs one point: 6 VALU + 1 trans.
    auto st1 = [&](float gx, float gy, float sx, float sy, float sv,
                   float& wa, float& va) {
        const float dx = sx - gx, dy = sy - gy;
        const float d2 = fmaf(dx, dx, fmaf(dy, dy, EPS2));
        const float r = __builtin_amdgcn_rcpf(d2);
        wa += r;
        va = fmaf(sv, r, va);
    };

    // layout: f0 = Ax Ay Av Bx | f1 = By Bv Cx Cy | f2 = Cv Dx Dy Dv
#pragma unroll 8
    for (int k = 0; k < S_MAX / 4; ++k) {
        const float4 f0 = st4[3 * k + 0];
        const float4 f1 = st4[3 * k + 1];
        const float4 f2 = st4[3 * k + 2];
        st1(gx0, gy0, f0.x, f0.y, f0.z, ws0a, vs0a);  // A
        st1(gx0, gy0, f0.w, f1.x, f1.y, ws0b, vs0b);  // B
        st1(gx0, gy0, f1.z, f1.w, f2.x, ws0a, vs0a);  // C
        st1(gx0, gy0, f2.y, f2.z, f2.w, ws0b, vs0b);  // D
        st1(gx1, gy1, f0.x, f0.y, f0.z, ws1a, vs1a);
        st1(gx1, gy1, f0.w, f1.x, f1.y, ws1b, vs1b);
        st1(gx1, gy1, f1.z, f1.w, f2.x, ws1a, vs1a);
        st1(gx1, gy1, f2.y, f2.z, f2.w, ws1b, vs1b);
    }

    const float r0 = (vs0a + vs0b) / (ws0a + ws0b);
    const float r1 = (vs1a + vs1b) / (ws1a + ws1b);
    ((float2*)out)[(size_t)b * (P / 2) + tid] = make_float2(r0, r1);
}

extern "C" void kernel_launch(void* const* d_in, const int* in_sizes, int n_in,
                              void* d_out, int out_size, void* d_ws, size_t ws_size,
                              hipStream_t stream) {
    const float* station_coords = (const float*)d_in[0];
    const float* station_values = (const float*)d_in[1];
    const float* grid_points    = (const float*)d_in[2];
    float* out = (float*)d_out;

    const int B = 2;
    const int S = in_sizes[1] / B;   // 512
    const int P = out_size / B;      // 131072

    dim3 grid(P / (BLOCK * GPT), B);  // 256 x 2 = 512 blocks, 2 per CU
    dim3 block(BLOCK);
    idw_kernel<<<grid, block, 0, stream>>>(station_coords, station_values,
                                           grid_points, out, P, S);
}

// Round 5
// 78.615 us; speedup vs baseline: 1.1212x; 1.1212x over previous
//
#include <hip/hip_runtime.h>

// IDW, POWER=2.0 -> w = 1/d2 (sqrt cancels). out = sum(w*v)/sum(w).
// B=2, P=131072, S=512.
// R10: post-mortems R6..R9:
//  - R9 (4x rcp, -22% VALU) was WORST (+8.6us) -> trans ops cost ~8
//    issue-cyc/wave64 and don't co-issue free. REVERT to R6's rcp-combine
//    (1 trans per 4 stations): 31 VALU + 1 trans/quad is the cheapest mix.
//  - R6 reproducibly best (79.5/79.7) -> kernel structure does move dur_us.
//  - At GPT=2: LDS-bus floor 15.4us/CU (3 ds_read_b128/chunk serve only 2
//    points; 8 waves/CU x 384 reads x 12cyc) ~= VALU floor 14us, and
//    per-chunk compute (132 issue-cyc) barely covers LDS latency -> both
//    resident waves stall together. Measured 39us = 2.8x floor.
//  Fix: GPT=4 -- trade TLP for ILP. Each chunk's 3 reads feed 4 points:
//    LDS bus halves (7.7us/CU), compute/chunk = 264 issue-cyc >> LDS
//    latency (~150cyc), so a SINGLE wave hides it via distance-2 rotation
//    (6 ds_read_b128 in flight; compiler emits fine-grained lgkmcnt).
//    1 wave/SIMD: no co-tenant on the VALU port; VGPR (~100) irrelevant.
// EPS2 folded into the d2 fma chain (exact at d2==0: w -> 1/EPS^2 like ref).

#define BLOCK 256
#define S_MAX 512
#define GPT 4

__global__ __launch_bounds__(BLOCK) void idw_kernel(
    const float* __restrict__ station_coords,  // (B, S, 2)
    const float* __restrict__ station_values,  // (B, S)
    const float* __restrict__ grid_points,     // (B, P, 2)
    float* __restrict__ out,                   // (B, P)
    int P, int S) {

    __shared__ float st[S_MAX * 3];  // packed {x,y,v}, 12B/station

    const int b = blockIdx.y;
    const float2* __restrict__ sc2 = (const float2*)(station_coords) + (size_t)b * S;
    const float*  __restrict__ svb = station_values + (size_t)b * S;

    for (int i = threadIdx.x; i < S; i += BLOCK) {
        const float2 c = sc2[i];
        st[3 * i + 0] = c.x;
        st[3 * i + 1] = c.y;
        st[3 * i + 2] = svb[i];
    }
    __syncthreads();

    const int tid = blockIdx.x * BLOCK + threadIdx.x;
    // 4 points per thread: 2 coalesced float4 loads (32B/lane).
    const float4* __restrict__ gp4 = (const float4*)grid_points + (size_t)b * (P / 2);
    const float4 ga = gp4[2 * tid + 0];
    const float4 gb = gp4[2 * tid + 1];
    const float gx0 = ga.x, gy0 = ga.y, gx1 = ga.z, gy1 = ga.w;
    const float gx2 = gb.x, gy2 = gb.y, gx3 = gb.z, gy3 = gb.w;

    constexpr float EPS  = 1.1920928955078125e-07f;
    constexpr float EPS2 = EPS * EPS;

    float ws0 = 0.0f, vs0 = 0.0f, ws1 = 0.0f, vs1 = 0.0f;
    float ws2 = 0.0f, vs2 = 0.0f, ws3 = 0.0f, vs3 = 0.0f;

    const float4* __restrict__ st4 = (const float4*)st;

    // 4 stations A,B,C,D vs one point: ~31 plain VALU + 1 rcp (R6 math).
    // layout: f0 = Ax Ay Av Bx | f1 = By Bv Cx Cy | f2 = Cv Dx Dy Dv
    auto quad = [&](float gx, float gy, float& ws, float& vs,
                    const float4& f0, const float4& f1, const float4& f2) {
        const float dxa = gx - f0.x, dya = gy - f0.y;
        const float a = fmaf(dxa, dxa, fmaf(dya, dya, EPS2));
        const float dxb = gx - f0.w, dyb = gy - f1.x;
        const float bq = fmaf(dxb, dxb, fmaf(dyb, dyb, EPS2));
        const float dxc = gx - f1.z, dyc = gy - f1.w;
        const float c = fmaf(dxc, dxc, fmaf(dyc, dyc, EPS2));
        const float dxd = gx - f2.y, dyd = gy - f2.z;
        const float d = fmaf(dxd, dxd, fmaf(dyd, dyd, EPS2));
        const float pab = a * bq, pcd = c * d;
        const float sab = a + bq, scd = c + d;
        const float nab = fmaf(f1.y, a, f0.z * bq);  // vB*a + vA*b
        const float ncd = fmaf(f2.w, c, f2.x * d);   // vD*c + vC*d
        const float r = __builtin_amdgcn_rcpf(pab * pcd);
        ws = fmaf(fmaf(sab, pcd, scd * pab), r, ws);
        vs = fmaf(fmaf(nab, pcd, ncd * pab), r, vs);
    };

    // Distance-2 rotation pipeline: 6 ds_read_b128 in flight.
    float4 a0 = st4[0], a1 = st4[1], a2 = st4[2];
    float4 b0 = st4[3], b1 = st4[4], b2 = st4[5];
#pragma unroll 2
    for (int k = 0; k < S_MAX / 4 - 2; ++k) {
        const float4 n0 = st4[3 * k + 6];
        const float4 n1 = st4[3 * k + 7];
        const float4 n2 = st4[3 * k + 8];
        quad(gx0, gy0, ws0, vs0, a0, a1, a2);
        quad(gx1, gy1, ws1, vs1, a0, a1, a2);
        quad(gx2, gy2, ws2, vs2, a0, a1, a2);
        quad(gx3, gy3, ws3, vs3, a0, a1, a2);
        a0 = b0; a1 = b1; a2 = b2;
        b0 = n0; b1 = n1; b2 = n2;
    }
    // Epilogue: chunks 126 and 127.
    quad(gx0, gy0, ws0, vs0, a0, a1, a2);
    quad(gx1, gy1, ws1, vs1, a0, a1, a2);
    quad(gx2, gy2, ws2, vs2, a0, a1, a2);
    quad(gx3, gy3, ws3, vs3, a0, a1, a2);
    quad(gx0, gy0, ws0, vs0, b0, b1, b2);
    quad(gx1, gy1, ws1, vs1, b0, b1, b2);
    quad(gx2, gy2, ws2, vs2, b0, b1, b2);
    quad(gx3, gy3, ws3, vs3, b0, b1, b2);

    const float4 res = make_float4(vs0 / ws0, vs1 / ws1, vs2 / ws2, vs3 / ws3);
    ((float4*)out)[(size_t)b * (P / 4) + tid] = res;
}

extern "C" void kernel_launch(void* const* d_in, const int* in_sizes, int n_in,
                              void* d_out, int out_size, void* d_ws, size_t ws_size,
                              hipStream_t stream) {
    const float* station_coords = (const float*)d_in[0];
    const float* station_values = (const float*)d_in[1];
    const float* grid_points    = (const float*)d_in[2];
    float* out = (float*)d_out;

    const int B = 2;
    const int S = in_sizes[1] / B;   // 512
    const int P = out_size / B;      // 131072

    dim3 grid(P / (BLOCK * GPT), B);  // 128 x 2 = 256 blocks, 1 per CU
    dim3 block(BLOCK);
    idw_kernel<<<grid, block, 0, stream>>>(station_coords, station_values,
                                           grid_points, out, P, S);
}